// Round 15
// baseline (186.012 us; speedup 1.0000x reference)
//
#include <hip/hip_runtime.h>

// ---------------------------------------------------------------------------
// EquivariantProductBasisBlock (MACE symmetric contraction + gate + linear)
// N=10000, C=128, D=9, S=10.
// R15 = R14 with the role-split + 9-shfl x assembly REVERTED to per-lane
// full-node loads (4 lanes share a node -> duplicate addresses collapse in
// the coalescer; R9 evidence: only +16% FETCH). Removes 9 DS ops from the
// front of every iteration's dependency chain and makes load->use direct,
// so the 2-deep prefetch actually decouples. Everything else unchanged.
// ---------------------------------------------------------------------------

#define NN 10000
#define CC 128
#define SS 10
#define NPB 1024
#define MAXBLK 20
#define NPAD (MAXBLK*NPB)        // 20480

typedef unsigned short u16;
typedef __attribute__((ext_vector_type(8))) short bf16x8;
typedef __attribute__((ext_vector_type(4))) float f32x4;

// A-frag layout per (c,s): [blk3][h3][lane64][e8] bf16 = 4608 u16 = 9 KB.
#define AFRAG_U16 4608

// ws layout (floats)
#define OFF_AF   0                          // 1280*4608 u16 = 2,949,120 f
#define OFF_F0   2949120                    // CC*NPAD   = 2,621,440
#define OFF_F1   5570560                    // 3*CC*NPAD = 7,864,320
#define OFF_GKF  13434880                   // 327,680 u16 = 163,840 f
#define OFF_LINF 13598720                   // 32,768 u16 = 16,384 f
#define OFF_ORD  13615104                   // NPAD ints
#define OFF_META 13635584                   // 64 ints

__device__ __forceinline__ u16 bf16rne(float f) {
    unsigned u = __float_as_uint(f);
    u += 0x7fffu + ((u >> 16) & 1u);
    return (u16)(u >> 16);
}
__device__ __forceinline__ float bf2f(u16 h) {
    return __uint_as_float(((unsigned)h) << 16);
}
__device__ __forceinline__ unsigned pk2(float lo, float hi) {
    unsigned r;
    asm("v_cvt_pk_bf16_f32 %0, %1, %2" : "=v"(r) : "v"(lo), "v"(hi));
    return r;
}

// ---------------- plan: species histogram + segment map + order init ----------------
__global__ __launch_bounds__(256) void k_plan(
    const int* __restrict__ sp, int* __restrict__ cursor,
    int* __restrict__ blk_sp, int* __restrict__ order) {
    __shared__ int cnt[SS];
    int t = threadIdx.x;
    if (t < SS) cnt[t] = 0;
    __syncthreads();
    for (int i = t; i < NN; i += 256) atomicAdd(&cnt[sp[i]], 1);
    __syncthreads();
    if (t == 0) {
        int pos = 0, b = 0;
        for (int s = 0; s < SS; ++s) {
            cursor[s] = pos;
            int nb = (cnt[s] + NPB - 1) / NPB;
            for (int i = 0; i < nb; ++i) blk_sp[b++] = s;
            pos += nb * NPB;
        }
        for (; b < MAXBLK; ++b) blk_sp[b] = -1;
    }
    for (int i = t; i < NPAD; i += 256) order[i] = -1;
}

__global__ void k_scatter(const int* __restrict__ sp, int* __restrict__ cursor,
                          int* __restrict__ order) {
    int n = blockIdx.x * 256 + threadIdx.x;
    if (n < NN) {
        int p = atomicAdd(&cursor[sp[n]], 1);
        order[p] = n;
    }
}

// ---------------- prep: build M2, rows at sec*12+idx (bf16 A-frags) ----------------
__global__ __launch_bounds__(512) void k_prep2(
    const float* __restrict__ u1_0e, const float* __restrict__ u2_0e, const float* __restrict__ u3_0e,
    const float* __restrict__ u1_1o, const float* __restrict__ u2_1o, const float* __restrict__ u3_1o,
    const float* __restrict__ w1_0e, const float* __restrict__ w2_0e, const float* __restrict__ w3_0e,
    const float* __restrict__ w1_1o, const float* __restrict__ w2_1o, const float* __restrict__ w3_1o,
    u16* __restrict__ af) {
    int row = blockIdx.x, s = blockIdx.y;
    int c = threadIdx.x & 127, q = threadIdx.x >> 7;    // q wave-uniform
    int sec = row / 12, idx = row % 12;
    u16* base = af + (size_t)(c * SS + s) * AFRAG_U16;
    int blk = row >> 4, r16 = row & 15;
    auto emit2 = [&](int h, int g, int e, float v) {
        base[(((blk * 3 + h) * 64 + g * 16 + r16) << 3) + e] = bf16rne(v);
    };
    auto emitq = [&](int a, int b, float v) {
        if (b == 8) {
            if (a == 8)      emit2(2, 0, 0, v);
            else if (a <= 5) emit2(2, 0, 2 + a, v);
            else if (a == 6) emit2(2, 2, 0, v);
            else             emit2(2, 3, 0, v);
        } else if (a < 4)    emit2(0, a, b, v);
        else                 emit2(1, a - 4, b, v);
    };
    auto emitl = [&](int j, float v) {
        if (j == 8)      emit2(2, 0, 1, v);
        else if (j <= 5) emit2(2, 1, 2 + j, v);
        else if (j == 6) emit2(2, 2, 1, v);
        else             emit2(2, 3, 1, v);
    };
    const int PQ[5] = {0, 12, 24, 35, 45};
    int pa = PQ[q], pb = PQ[q + 1];
    if (idx < 9) {
        int i = idx;
        if (sec < 3) {
            float w[30];
#pragma unroll 1
            for (int p = 0; p < 30; ++p) w[p] = w3_1o[(s * 30 + p) * CC + c];
            int k = 0;
#pragma unroll 1
            for (int a = 0; a < 9; ++a)
#pragma unroll 1
                for (int b = a; b < 9; ++b) {
                    if (k >= pa && k < pb) {
                        const float* ua = u3_1o + (size_t)((((sec * 9 + i) * 9 + a) * 9 + b)) * 30;
                        const float* ub = u3_1o + (size_t)((((sec * 9 + i) * 9 + b) * 9 + a)) * 30;
                        float acc = 0.f;
                        if (a == b) { for (int p = 0; p < 30; ++p) acc += ua[p] * w[p]; }
                        else        { for (int p = 0; p < 30; ++p) acc += (ua[p] + ub[p]) * w[p]; }
                        emitq(a, b, acc);
                    }
                    ++k;
                }
            if (q == 3) {
                float w2[4];
#pragma unroll
                for (int p = 0; p < 4; ++p) w2[p] = w2_1o[(s * 4 + p) * CC + c];
#pragma unroll 1
                for (int j = 0; j < 9; ++j) {
                    const float* u = u2_1o + (size_t)(((sec * 9 + i) * 9 + j)) * 4;
                    float acc = 0.f;
                    for (int p = 0; p < 4; ++p) acc += u[p] * w2[p];
                    emitl(j, acc);
                }
            }
        } else {
            float w[23];
#pragma unroll 1
            for (int p = 0; p < 23; ++p) w[p] = w3_0e[(s * 23 + p) * CC + c];
            int k = 0;
#pragma unroll 1
            for (int a = 0; a < 9; ++a)
#pragma unroll 1
                for (int b = a; b < 9; ++b) {
                    if (k >= pa && k < pb) {
                        const float* ua = u3_0e + (size_t)(((i * 9 + a) * 9 + b)) * 23;
                        const float* ub = u3_0e + (size_t)(((i * 9 + b) * 9 + a)) * 23;
                        float acc = 0.f;
                        if (a == b) { for (int p = 0; p < 23; ++p) acc += ua[p] * w[p]; }
                        else        { for (int p = 0; p < 23; ++p) acc += (ua[p] + ub[p]) * w[p]; }
                        emitq(a, b, acc);
                    }
                    ++k;
                }
            if (q == 3) {
                float w2[4];
#pragma unroll
                for (int p = 0; p < 4; ++p) w2[p] = w2_0e[(s * 4 + p) * CC + c];
#pragma unroll 1
                for (int j = 0; j < 9; ++j) {
                    const float* u = u2_0e + (size_t)((i * 9 + j)) * 4;
                    float acc = 0.f;
                    for (int p = 0; p < 4; ++p) acc += u[p] * w2[p];
                    emitl(j, acc);
                }
            }
        }
    } else if (idx == 9 && q == 0) {
        if (sec < 3) {
            float wv = w1_1o[s * CC + c];
#pragma unroll 1
            for (int i = 0; i < 9; ++i) emitl(i, u1_1o[sec * 9 + i] * wv);
        } else {
            float wv = w1_0e[s * CC + c];
#pragma unroll 1
            for (int i = 0; i < 9; ++i) emitl(i, u1_0e[i] * wv);
        }
    }
    // idx 10,11: zeros from memset
}

// ---------------- prep: gk and lin as B-fragment streams (bf16) ----------------
__global__ __launch_bounds__(256) void k_prepf(
    const float* __restrict__ gk, const float* __restrict__ lin0,
    const float* __restrict__ lin1, u16* __restrict__ gkf, u16* __restrict__ linf) {
    int b = blockIdx.x, t = threadIdx.x, lane = t & 63, ck = t >> 6;
    if (b < 160) {
        int s = b >> 4, kt = b & 15;
        int k = kt * 16 + (lane & 15);
        u16* dst = gkf + (((size_t)b * 4 + ck) * 64 + lane) * 8;
        const float* src = gk + (size_t)s * CC * 256;
#pragma unroll
        for (int e = 0; e < 8; ++e) {
            int c = ck * 32 + ((lane >> 4) & 3) * 8 + e;
            dst[e] = bf16rne(src[c * 256 + k]);
        }
    } else {
        int bb = b - 160;            // part*8 + kt
        int kt = bb & 7;
        int k = kt * 16 + (lane & 15);
        const float* src = (bb >> 3) ? lin1 : lin0;
        u16* dst = linf + (((size_t)bb * 4 + ck) * 64 + lane) * 8;
#pragma unroll
        for (int e = 0; e < 8; ++e) {
            int c = ck * 32 + ((lane >> 4) & 3) * 8 + e;
            dst[e] = bf16rne(src[c * CC + k]);
        }
    }
}

// ---------------- per-lane full-node x load ----------------
__device__ __forceinline__ void loadx(const float* __restrict__ nf, int n, int c,
                                      float* __restrict__ x) {
    if (n >= 0) {
        const float* r = nf + (size_t)n * 1152;
        x[0] = r[c];
        const float* r3 = r + 128 + c * 3;
        x[1] = r3[0]; x[2] = r3[1]; x[3] = r3[2];
        const float* r5 = r + 512 + c * 5;
        x[4] = r5[0]; x[5] = r5[1]; x[6] = r5[2]; x[7] = r5[3]; x[8] = r5[4];
    } else {
#pragma unroll
        for (int i = 0; i < 9; ++i) x[i] = 0.f;
    }
}

// ---------------- symmetric contraction via MFMA (per-wave, LDS-free) ----------
// 128-thr (2-wave) blocks; grid = 5120. bid decode puts channels c in groups
// of 16 on one XCD (xcd = c>>4). Each lane loads the FULL x of its n16 node
// (4 lanes duplicate -> coalescer collapses). x prefetched 2 subtiles deep;
// order 4 deep. Zero LDS, zero barriers, zero ds-ops before the epilogue.
__global__ __launch_bounds__(128) void k_contract(
    const float* __restrict__ nf, const int* __restrict__ order,
    const int* __restrict__ blk_sp, const u16* __restrict__ af_g,
    float* __restrict__ f0t, float* __restrict__ f1t) {
    int bid = blockIdx.x;                 // 0..5119
    int xcd = bid & 7;
    int r = bid >> 3;                     // 0..639
    int c = xcd * 16 + (r / 40);          // channel; c>>4 == xcd
    int t2 = r % 40;
    int seg = t2 >> 1, half = t2 & 1;
    int s = blk_sp[seg];
    if (s < 0) return;

    int tid = threadIdx.x;
    int lane = tid & 63;
    int wq = half * 2 + (tid >> 6);       // 0..3
    int n16 = lane & 15, gg = lane >> 4;

    const bf16x8* ab = (const bf16x8*)(af_g + (size_t)(c * SS + s) * AFRAG_U16);
    bf16x8 a00 = ab[0 * 64 + lane], a01 = ab[1 * 64 + lane], a02 = ab[2 * 64 + lane];
    bf16x8 a10 = ab[3 * 64 + lane], a11 = ab[4 * 64 + lane], a12 = ab[5 * 64 + lane];
    bf16x8 a20 = ab[6 * 64 + lane], a21 = ab[7 * 64 + lane], a22 = ab[8 * 64 + lane];

    int posw = seg * NPB + wq * 16 + n16;

    // pipelines: xc = x(sub), xn = x(sub+1); o2/o3 = order(sub+2 / sub+3)
    float xc[9], xn[9];
    loadx(nf, order[posw], c, xc);
    loadx(nf, order[posw + 64], c, xn);
    int o2 = order[posw + 128];
    int o3 = order[posw + 192];

#pragma unroll 1
    for (int sub = 0; sub < 16; ++sub) {
        // issue x loads for sub+2 (2-iteration latency budget)
        float xf[9];
#pragma unroll
        for (int i = 0; i < 9; ++i) xf[i] = 0.f;
        if (sub < 14) loadx(nf, o2, c, xf);
        int onew = (sub < 12) ? order[posw + (sub + 4) * 64] : -1;

        // ---- y fragments in-register (product form) ----
        float xa0 = (gg == 0) ? xc[0] : (gg == 1) ? xc[1] : (gg == 2) ? xc[2] : xc[3];
        float xa1 = (gg == 0) ? xc[4] : (gg == 1) ? xc[5] : (gg == 2) ? xc[6] : xc[7];
        float xa2 = (gg == 0) ? xc[8] : (gg == 1) ? 1.0f : (gg == 2) ? xc[6] : xc[7];
        uint4 q0, q1, q2;
        q0.x = pk2(xa0 * xc[0], xa0 * xc[1]);
        q0.y = pk2(xa0 * xc[2], xa0 * xc[3]);
        q0.z = pk2(xa0 * xc[4], xa0 * xc[5]);
        q0.w = pk2(xa0 * xc[6], xa0 * xc[7]);
        q1.x = pk2(xa1 * xc[0], xa1 * xc[1]);
        q1.y = pk2(xa1 * xc[2], xa1 * xc[3]);
        q1.z = pk2(xa1 * xc[4], xa1 * xc[5]);
        q1.w = pk2(xa1 * xc[6], xa1 * xc[7]);
        q2.x = pk2(xa2 * xc[8], xa2);
        q2.y = pk2(xa2 * xc[0], xa2 * xc[1]);
        q2.z = pk2(xa2 * xc[2], xa2 * xc[3]);
        q2.w = pk2(xa2 * xc[4], xa2 * xc[5]);
        bf16x8 y0 = __builtin_bit_cast(bf16x8, q0);
        bf16x8 y1 = __builtin_bit_cast(bf16x8, q1);
        bf16x8 y2 = __builtin_bit_cast(bf16x8, q2);

        // ---- 9 MFMAs ----
        f32x4 acc0 = {0.f, 0.f, 0.f, 0.f}, acc1 = acc0, acc2 = acc0;
        acc0 = __builtin_amdgcn_mfma_f32_16x16x32_bf16(a00, y0, acc0, 0, 0, 0);
        acc0 = __builtin_amdgcn_mfma_f32_16x16x32_bf16(a01, y1, acc0, 0, 0, 0);
        acc0 = __builtin_amdgcn_mfma_f32_16x16x32_bf16(a02, y2, acc0, 0, 0, 0);
        acc1 = __builtin_amdgcn_mfma_f32_16x16x32_bf16(a10, y0, acc1, 0, 0, 0);
        acc1 = __builtin_amdgcn_mfma_f32_16x16x32_bf16(a11, y1, acc1, 0, 0, 0);
        acc1 = __builtin_amdgcn_mfma_f32_16x16x32_bf16(a12, y2, acc1, 0, 0, 0);
        acc2 = __builtin_amdgcn_mfma_f32_16x16x32_bf16(a20, y0, acc2, 0, 0, 0);
        acc2 = __builtin_amdgcn_mfma_f32_16x16x32_bf16(a21, y1, acc2, 0, 0, 0);
        acc2 = __builtin_amdgcn_mfma_f32_16x16x32_bf16(a22, y2, acc2, 0, 0, 0);

        // ---- in-register epilogue (row = sec*12+idx layout) ----
        f32x4 eA = (gg == 0) ? acc0 : (gg == 1) ? acc2 : (gg == 2) ? acc1 : acc0;
        f32x4 eB = (gg == 0) ? acc1 : (gg == 1) ? acc0 : (gg == 2) ? acc2 : acc1;
        f32x4 eC = (gg == 0) ? acc2 : (gg == 1) ? acc1 : (gg == 2) ? acc0 : acc2;
        float dA = eA[0] * xc[0] + eA[1] * xc[1] + eA[2] * xc[2] + eA[3] * xc[3];
        float dB = eB[0] * xc[4] + eB[1] * xc[5] + eB[2] * xc[6] + eB[3] * xc[7];
        float dC = eC[0] * xc[8] + eC[1];
        float p0 = (gg == 0) ? dA : (gg == 1) ? dB : (gg == 2) ? dC : 0.f;
        float p1 = (gg == 0) ? dB : (gg == 1) ? dC : (gg == 2) ? 0.f : dA;
        float p2 = (gg == 0) ? dC : (gg == 1) ? 0.f : (gg == 2) ? dA : dB;
        float p3 = (gg == 0) ? 0.f : (gg == 1) ? dA : (gg == 2) ? dB : dC;
        p0 += __shfl_xor(p0, 16); p1 += __shfl_xor(p1, 16);
        p2 += __shfl_xor(p2, 16); p3 += __shfl_xor(p3, 16);
        p0 += __shfl_xor(p0, 32); p1 += __shfl_xor(p1, 32);
        p2 += __shfl_xor(p2, 32); p3 += __shfl_xor(p3, 32);
        float val = (gg == 0) ? p0 : (gg == 1) ? p1 : (gg == 2) ? p2 : p3;

        int pos = posw + sub * 64;
        if (gg == 3) f0t[(size_t)c * NPAD + pos] = val;
        else         f1t[(size_t)(c * 3 + gg) * NPAD + pos] = val;

        // rotate pipelines
#pragma unroll
        for (int i = 0; i < 9; ++i) { xc[i] = xn[i]; xn[i] = xf[i]; }
        o2 = o3; o3 = onew;
    }
}

// ---------------- fused gate + equivariant linear (MFMA) ----------------
#define GSTR 264
__global__ __launch_bounds__(256) void k_post(
    const float* __restrict__ f0t, const float* __restrict__ f1t,
    const u16* __restrict__ gkf, const u16* __restrict__ linf,
    const float* __restrict__ gb, const int* __restrict__ order,
    const int* __restrict__ blk_sp, float* __restrict__ out) {
    int tile = blockIdx.x;
    int s = blk_sp[tile >> 4];
    if (s < 0) return;
    int p0 = tile * 64;

    __shared__ __align__(16) u16 frag[4][4][64][8];   // 16 KB (A1, then A2)
    __shared__ __align__(16) u16 gate_l[64 * GSTR];   // 33 KB
    __shared__ int ord[64];

    int t = threadIdx.x, lane = t & 63, w = t >> 6;
    int l15 = lane & 15, lg = lane >> 4;
    if (t < 64) ord[t] = order[p0 + t];

    // stage A1 = scal (f0) bf16 fragments
#pragma unroll 1
    for (int it = 0; it < 32; ++it) {
        int posn = t & 63;
        int c = (t >> 6) + 4 * it;
        float v = f0t[(size_t)c * NPAD + p0 + posn];
        frag[posn >> 4][c >> 5][((c >> 3) & 3) * 16 + (posn & 15)][c & 7] = bf16rne(v);
    }
    __syncthreads();

    // GEMM1: gate[pos][k] = bias + sum_c scal[pos][c]*gk[c][k]
#pragma unroll 1
    for (int kt = 0; kt < 16; ++kt) {
        float bias = gb[s * 256 + kt * 16 + l15];
        f32x4 acc = {bias, bias, bias, bias};
#pragma unroll
        for (int ck = 0; ck < 4; ++ck) {
            bf16x8 a = *(const bf16x8*)&frag[w][ck][lane][0];
            bf16x8 b = *(const bf16x8*)&gkf[(((size_t)(s * 16 + kt)) * 4 + ck) * 512 + lane * 8];
            acc = __builtin_amdgcn_mfma_f32_16x16x32_bf16(a, b, acc, 0, 0, 0);
        }
#pragma unroll
        for (int r = 0; r < 4; ++r) {
            int posn = w * 16 + lg * 4 + r;
            gate_l[posn * GSTR + kt * 16 + l15] = bf16rne(acc[r]);
        }
    }
    __syncthreads();

    const float INV = 0.08838834764831845f;   // 1/sqrt(128)

    // GEMM2: p=0 -> f0*gate[:, :128] @ lin0 ; p=1..3 -> f1z*gate[:,128:] @ lin1
#pragma unroll 1
    for (int p = 0; p < 4; ++p) {
#pragma unroll 1
        for (int it = 0; it < 4; ++it) {
            int rr = it * 256 + t;                 // 0..1023
            int pt = rr >> 8, ck = (rr >> 6) & 3, l2 = rr & 63;
            int posn = pt * 16 + (l2 & 15);
            int cb = ck * 32 + (l2 >> 4) * 8;
            u16 res[8];
            if (p == 0) {
                bf16x8 a1 = *(const bf16x8*)&frag[pt][ck][l2][0];
                const u16* gp = &gate_l[posn * GSTR + cb];
#pragma unroll
                for (int e = 0; e < 8; ++e)
                    res[e] = bf16rne(bf2f((u16)a1[e]) * bf2f(gp[e]));
            } else {
                int z = p - 1;
                const u16* gp = &gate_l[posn * GSTR + 128 + cb];
#pragma unroll
                for (int e = 0; e < 8; ++e) {
                    float fv = f1t[((size_t)(cb + e) * 3 + z) * NPAD + p0 + posn];
                    res[e] = bf16rne(fv * bf2f(gp[e]));
                }
            }
            uint4 uv;
            uv.x = (unsigned)res[0] | ((unsigned)res[1] << 16);
            uv.y = (unsigned)res[2] | ((unsigned)res[3] << 16);
            uv.z = (unsigned)res[4] | ((unsigned)res[5] << 16);
            uv.w = (unsigned)res[6] | ((unsigned)res[7] << 16);
            *(uint4*)&frag[pt][ck][l2][0] = uv;
        }
        __syncthreads();

        int lbase = (p == 0) ? 0 : 8;
#pragma unroll 1
        for (int kt = 0; kt < 8; ++kt) {
            f32x4 acc = {0.f, 0.f, 0.f, 0.f};
#pragma unroll
            for (int ck = 0; ck < 4; ++ck) {
                bf16x8 a = *(const bf16x8*)&frag[w][ck][lane][0];
                bf16x8 b = *(const bf16x8*)&linf[(((size_t)(lbase + kt)) * 4 + ck) * 512 + lane * 8];
                acc = __builtin_amdgcn_mfma_f32_16x16x32_bf16(a, b, acc, 0, 0, 0);
            }
            int k = kt * 16 + l15;
            int kk = (p == 0) ? k : (128 + k * 3 + (p - 1));
#pragma unroll
            for (int r = 0; r < 4; ++r) {
                int posn = w * 16 + lg * 4 + r;
                int n = ord[posn];
                if (n >= 0) out[(size_t)n * 512 + kk] = acc[r] * INV;
            }
        }
        __syncthreads();
    }
}

// ---------------------------------------------------------------------------
extern "C" void kernel_launch(void* const* d_in, const int* in_sizes, int n_in,
                              void* d_out, int out_size, void* d_ws, size_t ws_size,
                              hipStream_t stream) {
    const float* nf    = (const float*)d_in[0];
    const int*   sp    = (const int*)  d_in[1];
    const float* u1_0e = (const float*)d_in[2];
    const float* u2_0e = (const float*)d_in[3];
    const float* u3_0e = (const float*)d_in[4];
    const float* u1_1o = (const float*)d_in[5];
    const float* u2_1o = (const float*)d_in[6];
    const float* u3_1o = (const float*)d_in[7];
    const float* w1_0e = (const float*)d_in[8];
    const float* w2_0e = (const float*)d_in[9];
    const float* w3_0e = (const float*)d_in[10];
    const float* w1_1o = (const float*)d_in[11];
    const float* w2_1o = (const float*)d_in[12];
    const float* w3_1o = (const float*)d_in[13];
    const float* gk    = (const float*)d_in[14];
    const float* gb    = (const float*)d_in[15];
    const float* lin0  = (const float*)d_in[16];
    const float* lin1  = (const float*)d_in[17];

    float* ws   = (float*)d_ws;
    u16*  af    = (u16*)(ws + OFF_AF);
    float* f0t  = ws + OFF_F0;
    float* f1t  = ws + OFF_F1;
    u16*  gkf   = (u16*)(ws + OFF_GKF);
    u16*  linf  = (u16*)(ws + OFF_LINF);
    int* order  = (int*)(ws + OFF_ORD);
    int* meta   = (int*)(ws + OFF_META);
    int* cursor = meta + 16;
    int* blk_sp = meta + 32;

    hipMemsetAsync(af, 0, (size_t)CC * SS * AFRAG_U16 * sizeof(u16), stream);
    k_plan<<<1, 256, 0, stream>>>(sp, cursor, blk_sp, order);
    k_scatter<<<40, 256, 0, stream>>>(sp, cursor, order);
    dim3 gp(48, SS);
    k_prep2<<<gp, 512, 0, stream>>>(u1_0e, u2_0e, u3_0e, u1_1o, u2_1o, u3_1o,
                                    w1_0e, w2_0e, w3_0e, w1_1o, w2_1o, w3_1o, af);
    k_prepf<<<176, 256, 0, stream>>>(gk, lin0, lin1, gkf, linf);
    k_contract<<<5120, 128, 0, stream>>>(nf, order, blk_sp, af, f0t, f1t);
    k_post<<<NPAD / 64, 256, 0, stream>>>(f0t, f1t, gkf, linf, gb, order, blk_sp,
                                          (float*)d_out);
}

// Round 16
// 180.706 us; speedup vs baseline: 1.0294x; 1.0294x over previous
//
#include <hip/hip_runtime.h>

// ---------------------------------------------------------------------------
// EquivariantProductBasisBlock (MACE symmetric contraction + gate + linear)
// N=10000, C=128, D=9, S=10.
// R16: aux-pipeline overhaul, contract frozen at R15.
//  - k_prep2: LDS row staging -> 12x16B stores/thread (was ~96 scattered u16)
//  - scatter+prep2+prepf fused into k_setup2 (block ranges); 8 -> 4 dispatches
//  - order-init + af-memset dropped; per-segment vend[] guards padding
//  - k_post grid (320,2): each half = gate + 2 passes (2x parallelism)
// ---------------------------------------------------------------------------

#define NN 10000
#define CC 128
#define SS 10
#define NPB 1024
#define MAXBLK 20
#define NPAD (MAXBLK*NPB)        // 20480

typedef unsigned short u16;
typedef __attribute__((ext_vector_type(8))) short bf16x8;
typedef __attribute__((ext_vector_type(4))) float f32x4;

#define AFRAG_U16 4608

// ws layout (floats)
#define OFF_AF   0                          // 1280*4608 u16 = 2,949,120 f
#define OFF_F0   2949120                    // CC*NPAD   = 2,621,440
#define OFF_F1   5570560                    // 3*CC*NPAD = 7,864,320
#define OFF_GKF  13434880                   // 327,680 u16 = 163,840 f
#define OFF_LINF 13598720                   // 32,768 u16 = 16,384 f
#define OFF_ORD  13615104                   // NPAD ints
#define OFF_META 13635584                   // 128 ints

__device__ __forceinline__ u16 bf16rne(float f) {
    unsigned u = __float_as_uint(f);
    u += 0x7fffu + ((u >> 16) & 1u);
    return (u16)(u >> 16);
}
__device__ __forceinline__ float bf2f(u16 h) {
    return __uint_as_float(((unsigned)h) << 16);
}
__device__ __forceinline__ unsigned pk2(float lo, float hi) {
    unsigned r;
    asm("v_cvt_pk_bf16_f32 %0, %1, %2" : "=v"(r) : "v"(lo), "v"(hi));
    return r;
}

// ---------------- plan: hist + segment map + vend (1 block) ----------------
__global__ __launch_bounds__(256) void k_plan(
    const int* __restrict__ sp, int* __restrict__ cursor,
    int* __restrict__ blk_sp, int* __restrict__ vend) {
    __shared__ int cnt[SS];
    int t = threadIdx.x;
    if (t < SS) cnt[t] = 0;
    __syncthreads();
    for (int i = t; i < NN; i += 256) atomicAdd(&cnt[sp[i]], 1);
    __syncthreads();
    if (t == 0) {
        int pos = 0, b = 0;
        for (int s = 0; s < SS; ++s) {
            cursor[s] = pos;
            int nb = (cnt[s] + NPB - 1) / NPB;
            for (int i = 0; i < nb; ++i) {
                blk_sp[b] = s;
                int rem = cnt[s] - i * NPB;
                vend[b] = rem > NPB ? NPB : rem;
                ++b;
            }
            pos += nb * NPB;
        }
        for (; b < MAXBLK; ++b) { blk_sp[b] = -1; vend[b] = 0; }
    }
}

// ---------------- fused setup: scatter | prep2 | prepf ----------------
// grid 735 x 128thr: [0,79) scatter; [79,559) prep2; [559,735) prepf
#define SC_BLK 79
#define P2_BLK 480
__global__ __launch_bounds__(128) void k_setup2(
    const int* __restrict__ sp, int* __restrict__ cursor, int* __restrict__ order,
    const float* __restrict__ u1_0e, const float* __restrict__ u2_0e, const float* __restrict__ u3_0e,
    const float* __restrict__ u1_1o, const float* __restrict__ u2_1o, const float* __restrict__ u3_1o,
    const float* __restrict__ w1_0e, const float* __restrict__ w2_0e, const float* __restrict__ w3_0e,
    const float* __restrict__ w1_1o, const float* __restrict__ w2_1o, const float* __restrict__ w3_1o,
    u16* __restrict__ af,
    const float* __restrict__ gk, const float* __restrict__ lin0,
    const float* __restrict__ lin1, u16* __restrict__ gkf, u16* __restrict__ linf) {
    __shared__ uint rowbuf[128][50];    // 100 u16 per thread row (25.6 KB)
    int bid = blockIdx.x, t = threadIdx.x;

    if (bid < SC_BLK) {
        // ---- scatter ----
        int n = bid * 128 + t;
        if (n < NN) {
            int p = atomicAdd(&cursor[sp[n]], 1);
            order[p] = n;
        }
        return;
    }
    if (bid < SC_BLK + P2_BLK) {
        // ---- prep2: block = (row, s), thread = c ----
        int b2 = bid - SC_BLK;
        int row = b2 % 48, s = b2 / 48;
        int c = t;
        int sec = row / 12, idx = row % 12;
        u16* myrow = (u16*)&rowbuf[c][0];
#pragma unroll
        for (int i = 0; i < 50; ++i) rowbuf[c][i] = 0u;
        auto emit2 = [&](int h, int g, int e, float v) {
            myrow[(h * 4 + g) * 8 + e] = bf16rne(v);
        };
        auto emitq = [&](int a, int b, float v) {
            if (b == 8) {
                if (a == 8)      emit2(2, 0, 0, v);
                else if (a <= 5) emit2(2, 0, 2 + a, v);
                else if (a == 6) emit2(2, 2, 0, v);
                else             emit2(2, 3, 0, v);
            } else if (a < 4)    emit2(0, a, b, v);
            else                 emit2(1, a - 4, b, v);
        };
        auto emitl = [&](int j, float v) {
            if (j == 8)      emit2(2, 0, 1, v);
            else if (j <= 5) emit2(2, 1, 2 + j, v);
            else if (j == 6) emit2(2, 2, 1, v);
            else             emit2(2, 3, 1, v);
        };
        if (idx < 9) {
            int i = idx;
            if (sec < 3) {
                float w[30];
#pragma unroll 1
                for (int p = 0; p < 30; ++p) w[p] = w3_1o[(s * 30 + p) * CC + c];
#pragma unroll 1
                for (int a = 0; a < 9; ++a)
#pragma unroll 1
                    for (int b = a; b < 9; ++b) {
                        const float* ua = u3_1o + (size_t)((((sec * 9 + i) * 9 + a) * 9 + b)) * 30;
                        const float* ub = u3_1o + (size_t)((((sec * 9 + i) * 9 + b) * 9 + a)) * 30;
                        float acc = 0.f;
                        if (a == b) { for (int p = 0; p < 30; ++p) acc += ua[p] * w[p]; }
                        else        { for (int p = 0; p < 30; ++p) acc += (ua[p] + ub[p]) * w[p]; }
                        emitq(a, b, acc);
                    }
                float w2[4];
#pragma unroll
                for (int p = 0; p < 4; ++p) w2[p] = w2_1o[(s * 4 + p) * CC + c];
#pragma unroll 1
                for (int j = 0; j < 9; ++j) {
                    const float* u = u2_1o + (size_t)(((sec * 9 + i) * 9 + j)) * 4;
                    float acc = 0.f;
                    for (int p = 0; p < 4; ++p) acc += u[p] * w2[p];
                    emitl(j, acc);
                }
            } else {
                float w[23];
#pragma unroll 1
                for (int p = 0; p < 23; ++p) w[p] = w3_0e[(s * 23 + p) * CC + c];
#pragma unroll 1
                for (int a = 0; a < 9; ++a)
#pragma unroll 1
                    for (int b = a; b < 9; ++b) {
                        const float* ua = u3_0e + (size_t)(((i * 9 + a) * 9 + b)) * 23;
                        const float* ub = u3_0e + (size_t)(((i * 9 + b) * 9 + a)) * 23;
                        float acc = 0.f;
                        if (a == b) { for (int p = 0; p < 23; ++p) acc += ua[p] * w[p]; }
                        else        { for (int p = 0; p < 23; ++p) acc += (ua[p] + ub[p]) * w[p]; }
                        emitq(a, b, acc);
                    }
                float w2[4];
#pragma unroll
                for (int p = 0; p < 4; ++p) w2[p] = w2_0e[(s * 4 + p) * CC + c];
#pragma unroll 1
                for (int j = 0; j < 9; ++j) {
                    const float* u = u2_0e + (size_t)((i * 9 + j)) * 4;
                    float acc = 0.f;
                    for (int p = 0; p < 4; ++p) acc += u[p] * w2[p];
                    emitl(j, acc);
                }
            }
        } else if (idx == 9) {
            if (sec < 3) {
                float wv = w1_1o[s * CC + c];
#pragma unroll 1
                for (int i = 0; i < 9; ++i) emitl(i, u1_1o[sec * 9 + i] * wv);
            } else {
                float wv = w1_0e[s * CC + c];
#pragma unroll 1
                for (int i = 0; i < 9; ++i) emitl(i, u1_0e[i] * wv);
            }
        }
        // idx 10,11: zeros already in rowbuf
        __syncthreads();   // fence before typed readback (R10 TBAA lesson)
        u16* dstbase = af + (size_t)(c * SS + s) * AFRAG_U16;
        int blk = row >> 4, r16 = row & 15;
#pragma unroll
        for (int h = 0; h < 3; ++h)
#pragma unroll
            for (int g = 0; g < 4; ++g) {
                int chunk = (h * 4 + g) * 8;
                uint2 v0 = *(uint2*)&myrow[chunk];
                uint2 v1 = *(uint2*)&myrow[chunk + 4];
                uint4 v = {v0.x, v0.y, v1.x, v1.y};
                *(uint4*)&dstbase[(size_t)((blk * 3 + h) * 64 + g * 16 + r16) * 8] = v;
            }
        return;
    }
    // ---- prepf ----
    {
        int b = bid - (SC_BLK + P2_BLK);   // 0..175
        int lane = t & 63;
#pragma unroll
        for (int ch = 0; ch < 2; ++ch) {
            int ck = (t >> 6) + 2 * ch;
            if (b < 160) {
                int s = b >> 4, kt = b & 15;
                int k = kt * 16 + (lane & 15);
                u16* dst = gkf + (((size_t)b * 4 + ck) * 64 + lane) * 8;
                const float* src = gk + (size_t)s * CC * 256;
#pragma unroll
                for (int e = 0; e < 8; ++e) {
                    int c = ck * 32 + ((lane >> 4) & 3) * 8 + e;
                    dst[e] = bf16rne(src[c * 256 + k]);
                }
            } else {
                int bb = b - 160;
                int kt = bb & 7;
                int k = kt * 16 + (lane & 15);
                const float* src = (bb >> 3) ? lin1 : lin0;
                u16* dst = linf + (((size_t)bb * 4 + ck) * 64 + lane) * 8;
#pragma unroll
                for (int e = 0; e < 8; ++e) {
                    int c = ck * 32 + ((lane >> 4) & 3) * 8 + e;
                    dst[e] = bf16rne(src[c * CC + k]);
                }
            }
        }
    }
}

// ---------------- per-lane full-node x load ----------------
__device__ __forceinline__ void loadx(const float* __restrict__ nf, int n, int c,
                                      float* __restrict__ x) {
    if (n >= 0) {
        const float* r = nf + (size_t)n * 1152;
        x[0] = r[c];
        const float* r3 = r + 128 + c * 3;
        x[1] = r3[0]; x[2] = r3[1]; x[3] = r3[2];
        const float* r5 = r + 512 + c * 5;
        x[4] = r5[0]; x[5] = r5[1]; x[6] = r5[2]; x[7] = r5[3]; x[8] = r5[4];
    } else {
#pragma unroll
        for (int i = 0; i < 9; ++i) x[i] = 0.f;
    }
}

// ---------------- symmetric contraction via MFMA (per-wave, LDS-free) ----------
__global__ __launch_bounds__(128) void k_contract(
    const float* __restrict__ nf, const int* __restrict__ order,
    const int* __restrict__ blk_sp, const int* __restrict__ vend,
    const u16* __restrict__ af_g,
    float* __restrict__ f0t, float* __restrict__ f1t) {
    int bid = blockIdx.x;                 // 0..5119
    int xcd = bid & 7;
    int r = bid >> 3;
    int c = xcd * 16 + (r / 40);
    int t2 = r % 40;
    int seg = t2 >> 1, half = t2 & 1;
    int s = blk_sp[seg];
    if (s < 0) return;
    int lim = seg * NPB + vend[seg];      // valid order[] positions < lim

    int tid = threadIdx.x;
    int lane = tid & 63;
    int wq = half * 2 + (tid >> 6);
    int n16 = lane & 15, gg = lane >> 4;

    const bf16x8* ab = (const bf16x8*)(af_g + (size_t)(c * SS + s) * AFRAG_U16);
    bf16x8 a00 = ab[0 * 64 + lane], a01 = ab[1 * 64 + lane], a02 = ab[2 * 64 + lane];
    bf16x8 a10 = ab[3 * 64 + lane], a11 = ab[4 * 64 + lane], a12 = ab[5 * 64 + lane];
    bf16x8 a20 = ab[6 * 64 + lane], a21 = ab[7 * 64 + lane], a22 = ab[8 * 64 + lane];

    int posw = seg * NPB + wq * 16 + n16;

    float xc[9], xn[9];
    loadx(nf, (posw < lim) ? order[posw] : -1, c, xc);
    loadx(nf, (posw + 64 < lim) ? order[posw + 64] : -1, c, xn);
    int o2 = (posw + 128 < lim) ? order[posw + 128] : -1;
    int o3 = (posw + 192 < lim) ? order[posw + 192] : -1;

#pragma unroll 1
    for (int sub = 0; sub < 16; ++sub) {
        float xf[9];
#pragma unroll
        for (int i = 0; i < 9; ++i) xf[i] = 0.f;
        if (sub < 14) loadx(nf, o2, c, xf);
        int onew = (sub < 12 && posw + (sub + 4) * 64 < lim)
                   ? order[posw + (sub + 4) * 64] : -1;

        float xa0 = (gg == 0) ? xc[0] : (gg == 1) ? xc[1] : (gg == 2) ? xc[2] : xc[3];
        float xa1 = (gg == 0) ? xc[4] : (gg == 1) ? xc[5] : (gg == 2) ? xc[6] : xc[7];
        float xa2 = (gg == 0) ? xc[8] : (gg == 1) ? 1.0f : (gg == 2) ? xc[6] : xc[7];
        uint4 q0, q1, q2;
        q0.x = pk2(xa0 * xc[0], xa0 * xc[1]);
        q0.y = pk2(xa0 * xc[2], xa0 * xc[3]);
        q0.z = pk2(xa0 * xc[4], xa0 * xc[5]);
        q0.w = pk2(xa0 * xc[6], xa0 * xc[7]);
        q1.x = pk2(xa1 * xc[0], xa1 * xc[1]);
        q1.y = pk2(xa1 * xc[2], xa1 * xc[3]);
        q1.z = pk2(xa1 * xc[4], xa1 * xc[5]);
        q1.w = pk2(xa1 * xc[6], xa1 * xc[7]);
        q2.x = pk2(xa2 * xc[8], xa2);
        q2.y = pk2(xa2 * xc[0], xa2 * xc[1]);
        q2.z = pk2(xa2 * xc[2], xa2 * xc[3]);
        q2.w = pk2(xa2 * xc[4], xa2 * xc[5]);
        bf16x8 y0 = __builtin_bit_cast(bf16x8, q0);
        bf16x8 y1 = __builtin_bit_cast(bf16x8, q1);
        bf16x8 y2 = __builtin_bit_cast(bf16x8, q2);

        f32x4 acc0 = {0.f, 0.f, 0.f, 0.f}, acc1 = acc0, acc2 = acc0;
        acc0 = __builtin_amdgcn_mfma_f32_16x16x32_bf16(a00, y0, acc0, 0, 0, 0);
        acc0 = __builtin_amdgcn_mfma_f32_16x16x32_bf16(a01, y1, acc0, 0, 0, 0);
        acc0 = __builtin_amdgcn_mfma_f32_16x16x32_bf16(a02, y2, acc0, 0, 0, 0);
        acc1 = __builtin_amdgcn_mfma_f32_16x16x32_bf16(a10, y0, acc1, 0, 0, 0);
        acc1 = __builtin_amdgcn_mfma_f32_16x16x32_bf16(a11, y1, acc1, 0, 0, 0);
        acc1 = __builtin_amdgcn_mfma_f32_16x16x32_bf16(a12, y2, acc1, 0, 0, 0);
        acc2 = __builtin_amdgcn_mfma_f32_16x16x32_bf16(a20, y0, acc2, 0, 0, 0);
        acc2 = __builtin_amdgcn_mfma_f32_16x16x32_bf16(a21, y1, acc2, 0, 0, 0);
        acc2 = __builtin_amdgcn_mfma_f32_16x16x32_bf16(a22, y2, acc2, 0, 0, 0);

        f32x4 eA = (gg == 0) ? acc0 : (gg == 1) ? acc2 : (gg == 2) ? acc1 : acc0;
        f32x4 eB = (gg == 0) ? acc1 : (gg == 1) ? acc0 : (gg == 2) ? acc2 : acc1;
        f32x4 eC = (gg == 0) ? acc2 : (gg == 1) ? acc1 : (gg == 2) ? acc0 : acc2;
        float dA = eA[0] * xc[0] + eA[1] * xc[1] + eA[2] * xc[2] + eA[3] * xc[3];
        float dB = eB[0] * xc[4] + eB[1] * xc[5] + eB[2] * xc[6] + eB[3] * xc[7];
        float dC = eC[0] * xc[8] + eC[1];
        float p0 = (gg == 0) ? dA : (gg == 1) ? dB : (gg == 2) ? dC : 0.f;
        float p1 = (gg == 0) ? dB : (gg == 1) ? dC : (gg == 2) ? 0.f : dA;
        float p2 = (gg == 0) ? dC : (gg == 1) ? 0.f : (gg == 2) ? dA : dB;
        float p3 = (gg == 0) ? 0.f : (gg == 1) ? dA : (gg == 2) ? dB : dC;
        p0 += __shfl_xor(p0, 16); p1 += __shfl_xor(p1, 16);
        p2 += __shfl_xor(p2, 16); p3 += __shfl_xor(p3, 16);
        p0 += __shfl_xor(p0, 32); p1 += __shfl_xor(p1, 32);
        p2 += __shfl_xor(p2, 32); p3 += __shfl_xor(p3, 32);
        float val = (gg == 0) ? p0 : (gg == 1) ? p1 : (gg == 2) ? p2 : p3;

        int pos = posw + sub * 64;
        if (gg == 3) f0t[(size_t)c * NPAD + pos] = val;
        else         f1t[(size_t)(c * 3 + gg) * NPAD + pos] = val;

#pragma unroll
        for (int i = 0; i < 9; ++i) { xc[i] = xn[i]; xn[i] = xf[i]; }
        o2 = o3; o3 = onew;
    }
}

// ---------------- fused gate + equivariant linear (MFMA), 2-way split ----------
#define GSTR 264
__global__ __launch_bounds__(256) void k_post(
    const float* __restrict__ f0t, const float* __restrict__ f1t,
    const u16* __restrict__ gkf, const u16* __restrict__ linf,
    const float* __restrict__ gb, const int* __restrict__ order,
    const int* __restrict__ blk_sp, const int* __restrict__ vend,
    float* __restrict__ out) {
    int tile = blockIdx.x;
    int half = blockIdx.y;                // 0: passes 0,1   1: passes 2,3
    int s = blk_sp[tile >> 4];
    if (s < 0) return;
    int p0 = tile * 64;
    int vv = vend[tile >> 4];
    int boff = (tile & 15) * 64;          // tile offset within segment

    __shared__ __align__(16) u16 frag[4][4][64][8];
    __shared__ __align__(16) u16 gate_l[64 * GSTR];
    __shared__ int ord[64];

    int t = threadIdx.x, lane = t & 63, w = t >> 6;
    int l15 = lane & 15, lg = lane >> 4;
    if (t < 64) ord[t] = (boff + t < vv) ? order[p0 + t] : -1;

    // stage A1 = scal (f0) bf16 fragments
#pragma unroll 1
    for (int it = 0; it < 32; ++it) {
        int posn = t & 63;
        int c = (t >> 6) + 4 * it;
        float v = f0t[(size_t)c * NPAD + p0 + posn];
        frag[posn >> 4][c >> 5][((c >> 3) & 3) * 16 + (posn & 15)][c & 7] = bf16rne(v);
    }
    __syncthreads();

    // GEMM1: gate (computed by both halves)
#pragma unroll 1
    for (int kt = 0; kt < 16; ++kt) {
        float bias = gb[s * 256 + kt * 16 + l15];
        f32x4 acc = {bias, bias, bias, bias};
#pragma unroll
        for (int ck = 0; ck < 4; ++ck) {
            bf16x8 a = *(const bf16x8*)&frag[w][ck][lane][0];
            bf16x8 b = *(const bf16x8*)&gkf[(((size_t)(s * 16 + kt)) * 4 + ck) * 512 + lane * 8];
            acc = __builtin_amdgcn_mfma_f32_16x16x32_bf16(a, b, acc, 0, 0, 0);
        }
#pragma unroll
        for (int r = 0; r < 4; ++r) {
            int posn = w * 16 + lg * 4 + r;
            gate_l[posn * GSTR + kt * 16 + l15] = bf16rne(acc[r]);
        }
    }
    __syncthreads();

    const float INV = 0.08838834764831845f;   // 1/sqrt(128)

#pragma unroll 1
    for (int p = 2 * half; p < 2 * half + 2; ++p) {
#pragma unroll 1
        for (int it = 0; it < 4; ++it) {
            int rr = it * 256 + t;
            int pt = rr >> 8, ck = (rr >> 6) & 3, l2 = rr & 63;
            int posn = pt * 16 + (l2 & 15);
            int cb = ck * 32 + (l2 >> 4) * 8;
            u16 res[8];
            if (p == 0) {
                bf16x8 a1 = *(const bf16x8*)&frag[pt][ck][l2][0];
                const u16* gp = &gate_l[posn * GSTR + cb];
#pragma unroll
                for (int e = 0; e < 8; ++e)
                    res[e] = bf16rne(bf2f((u16)a1[e]) * bf2f(gp[e]));
            } else {
                int z = p - 1;
                const u16* gp = &gate_l[posn * GSTR + 128 + cb];
#pragma unroll
                for (int e = 0; e < 8; ++e) {
                    float fv = f1t[((size_t)(cb + e) * 3 + z) * NPAD + p0 + posn];
                    res[e] = bf16rne(fv * bf2f(gp[e]));
                }
            }
            uint4 uv;
            uv.x = (unsigned)res[0] | ((unsigned)res[1] << 16);
            uv.y = (unsigned)res[2] | ((unsigned)res[3] << 16);
            uv.z = (unsigned)res[4] | ((unsigned)res[5] << 16);
            uv.w = (unsigned)res[6] | ((unsigned)res[7] << 16);
            *(uint4*)&frag[pt][ck][l2][0] = uv;
        }
        __syncthreads();

        int lbase = (p == 0) ? 0 : 8;
#pragma unroll 1
        for (int kt = 0; kt < 8; ++kt) {
            f32x4 acc = {0.f, 0.f, 0.f, 0.f};
#pragma unroll
            for (int ck = 0; ck < 4; ++ck) {
                bf16x8 a = *(const bf16x8*)&frag[w][ck][lane][0];
                bf16x8 b = *(const bf16x8*)&linf[(((size_t)(lbase + kt)) * 4 + ck) * 512 + lane * 8];
                acc = __builtin_amdgcn_mfma_f32_16x16x32_bf16(a, b, acc, 0, 0, 0);
            }
            int k = kt * 16 + l15;
            int kk = (p == 0) ? k : (128 + k * 3 + (p - 1));
#pragma unroll
            for (int r = 0; r < 4; ++r) {
                int posn = w * 16 + lg * 4 + r;
                int n = ord[posn];
                if (n >= 0) out[(size_t)n * 512 + kk] = acc[r] * INV;
            }
        }
        __syncthreads();
    }
}

// ---------------------------------------------------------------------------
extern "C" void kernel_launch(void* const* d_in, const int* in_sizes, int n_in,
                              void* d_out, int out_size, void* d_ws, size_t ws_size,
                              hipStream_t stream) {
    const float* nf    = (const float*)d_in[0];
    const int*   sp    = (const int*)  d_in[1];
    const float* u1_0e = (const float*)d_in[2];
    const float* u2_0e = (const float*)d_in[3];
    const float* u3_0e = (const float*)d_in[4];
    const float* u1_1o = (const float*)d_in[5];
    const float* u2_1o = (const float*)d_in[6];
    const float* u3_1o = (const float*)d_in[7];
    const float* w1_0e = (const float*)d_in[8];
    const float* w2_0e = (const float*)d_in[9];
    const float* w3_0e = (const float*)d_in[10];
    const float* w1_1o = (const float*)d_in[11];
    const float* w2_1o = (const float*)d_in[12];
    const float* w3_1o = (const float*)d_in[13];
    const float* gk    = (const float*)d_in[14];
    const float* gb    = (const float*)d_in[15];
    const float* lin0  = (const float*)d_in[16];
    const float* lin1  = (const float*)d_in[17];

    float* ws   = (float*)d_ws;
    u16*  af    = (u16*)(ws + OFF_AF);
    float* f0t  = ws + OFF_F0;
    float* f1t  = ws + OFF_F1;
    u16*  gkf   = (u16*)(ws + OFF_GKF);
    u16*  linf  = (u16*)(ws + OFF_LINF);
    int* order  = (int*)(ws + OFF_ORD);
    int* meta   = (int*)(ws + OFF_META);
    int* cursor = meta + 16;
    int* blk_sp = meta + 32;
    int* vend   = meta + 64;

    k_plan<<<1, 256, 0, stream>>>(sp, cursor, blk_sp, vend);
    k_setup2<<<SC_BLK + P2_BLK + 176, 128, 0, stream>>>(
        sp, cursor, order,
        u1_0e, u2_0e, u3_0e, u1_1o, u2_1o, u3_1o,
        w1_0e, w2_0e, w3_0e, w1_1o, w2_1o, w3_1o, af,
        gk, lin0, lin1, gkf, linf);
    k_contract<<<5120, 128, 0, stream>>>(nf, order, blk_sp, vend, af, f0t, f1t);
    dim3 gpost(NPAD / 64, 2);
    k_post<<<gpost, 256, 0, stream>>>(f0t, f1t, gkf, linf, gb, order, blk_sp, vend,
                                      (float*)d_out);
}

// Round 17
// 158.795 us; speedup vs baseline: 1.1714x; 1.1380x over previous
//
#include <hip/hip_runtime.h>

// ---------------------------------------------------------------------------
// EquivariantProductBasisBlock (MACE symmetric contraction + gate + linear)
// N=10000, C=128, D=9, S=10.
// R17 = R16 with k_setup2 at 512 threads: prep2 restores the c(128)xq(4)
// pair-quarter split (R16 accidentally dropped it -> 88us serial chain) and
// fully unrolls the p-dots (uniform loads batch as scalar loads). LDS rowbuf
// stride 48 uints (16B-aligned), cooperative zero/emit/readback with barriers.
// Contract/post unchanged from R16.
// ---------------------------------------------------------------------------

#define NN 10000
#define CC 128
#define SS 10
#define NPB 1024
#define MAXBLK 20
#define NPAD (MAXBLK*NPB)        // 20480

typedef unsigned short u16;
typedef __attribute__((ext_vector_type(8))) short bf16x8;
typedef __attribute__((ext_vector_type(4))) float f32x4;

#define AFRAG_U16 4608

// ws layout (floats)
#define OFF_AF   0                          // 1280*4608 u16 = 2,949,120 f
#define OFF_F0   2949120                    // CC*NPAD   = 2,621,440
#define OFF_F1   5570560                    // 3*CC*NPAD = 7,864,320
#define OFF_GKF  13434880                   // 327,680 u16 = 163,840 f
#define OFF_LINF 13598720                   // 32,768 u16 = 16,384 f
#define OFF_ORD  13615104                   // NPAD ints
#define OFF_META 13635584                   // 128 ints

__device__ __forceinline__ u16 bf16rne(float f) {
    unsigned u = __float_as_uint(f);
    u += 0x7fffu + ((u >> 16) & 1u);
    return (u16)(u >> 16);
}
__device__ __forceinline__ float bf2f(u16 h) {
    return __uint_as_float(((unsigned)h) << 16);
}
__device__ __forceinline__ unsigned pk2(float lo, float hi) {
    unsigned r;
    asm("v_cvt_pk_bf16_f32 %0, %1, %2" : "=v"(r) : "v"(lo), "v"(hi));
    return r;
}

// ---------------- plan: hist + segment map + vend (1 block) ----------------
__global__ __launch_bounds__(256) void k_plan(
    const int* __restrict__ sp, int* __restrict__ cursor,
    int* __restrict__ blk_sp, int* __restrict__ vend) {
    __shared__ int cnt[SS];
    int t = threadIdx.x;
    if (t < SS) cnt[t] = 0;
    __syncthreads();
    for (int i = t; i < NN; i += 256) atomicAdd(&cnt[sp[i]], 1);
    __syncthreads();
    if (t == 0) {
        int pos = 0, b = 0;
        for (int s = 0; s < SS; ++s) {
            cursor[s] = pos;
            int nb = (cnt[s] + NPB - 1) / NPB;
            for (int i = 0; i < nb; ++i) {
                blk_sp[b] = s;
                int rem = cnt[s] - i * NPB;
                vend[b] = rem > NPB ? NPB : rem;
                ++b;
            }
            pos += nb * NPB;
        }
        for (; b < MAXBLK; ++b) { blk_sp[b] = -1; vend[b] = 0; }
    }
}

// ---------------- fused setup: scatter | prep2 | prepf (512 thr) ----------------
// grid 588: [0,20) scatter; [20,500) prep2 (row,s) c128 x q4; [500,588) prepf x2
#define SC_BLK 20
#define P2_BLK 480
__global__ __launch_bounds__(512) void k_setup2(
    const int* __restrict__ sp, int* __restrict__ cursor, int* __restrict__ order,
    const float* __restrict__ u1_0e, const float* __restrict__ u2_0e, const float* __restrict__ u3_0e,
    const float* __restrict__ u1_1o, const float* __restrict__ u2_1o, const float* __restrict__ u3_1o,
    const float* __restrict__ w1_0e, const float* __restrict__ w2_0e, const float* __restrict__ w3_0e,
    const float* __restrict__ w1_1o, const float* __restrict__ w2_1o, const float* __restrict__ w3_1o,
    u16* __restrict__ af,
    const float* __restrict__ gk, const float* __restrict__ lin0,
    const float* __restrict__ lin1, u16* __restrict__ gkf, u16* __restrict__ linf) {
    __shared__ __align__(16) uint rowbuf[128 * 48];   // 24.6 KB; 48-uint rows
    int bid = blockIdx.x, t = threadIdx.x;

    if (bid < SC_BLK) {
        // ---- scatter ----
        int n = bid * 512 + t;
        if (n < NN) {
            int p = atomicAdd(&cursor[sp[n]], 1);
            order[p] = n;
        }
        return;
    }
    if (bid < SC_BLK + P2_BLK) {
        // ---- prep2: block = (row, s); thread = c(128) x q(4) ----
        int b2 = bid - SC_BLK;
        int row = b2 % 48, s = b2 / 48;
        int c = t & 127, q = t >> 7;            // q wave-uniform
        int sec = row / 12, idx = row % 12;
        u16* myrow = (u16*)&rowbuf[c * 48];
        for (int i = t; i < 128 * 48; i += 512) rowbuf[i] = 0u;
        __syncthreads();
        auto emit2 = [&](int h, int g, int e, float v) {
            myrow[(h * 4 + g) * 8 + e] = bf16rne(v);
        };
        auto emitq = [&](int a, int b, float v) {
            if (b == 8) {
                if (a == 8)      emit2(2, 0, 0, v);
                else if (a <= 5) emit2(2, 0, 2 + a, v);
                else if (a == 6) emit2(2, 2, 0, v);
                else             emit2(2, 3, 0, v);
            } else if (a < 4)    emit2(0, a, b, v);
            else                 emit2(1, a - 4, b, v);
        };
        auto emitl = [&](int j, float v) {
            if (j == 8)      emit2(2, 0, 1, v);
            else if (j <= 5) emit2(2, 1, 2 + j, v);
            else if (j == 6) emit2(2, 2, 1, v);
            else             emit2(2, 3, 1, v);
        };
        const int PQ[5] = {0, 12, 24, 35, 45};
        int pa = PQ[q], pb = PQ[q + 1];
        if (idx < 9) {
            int i = idx;
            if (sec < 3) {
                float w[30];
#pragma unroll
                for (int p = 0; p < 30; ++p) w[p] = w3_1o[(s * 30 + p) * CC + c];
                int k = 0;
#pragma unroll 1
                for (int a = 0; a < 9; ++a)
#pragma unroll 1
                    for (int b = a; b < 9; ++b) {
                        if (k >= pa && k < pb) {
                            const float* ua = u3_1o + (size_t)((((sec * 9 + i) * 9 + a) * 9 + b)) * 30;
                            const float* ub = u3_1o + (size_t)((((sec * 9 + i) * 9 + b) * 9 + a)) * 30;
                            float acc = 0.f;
                            if (a == b) {
#pragma unroll
                                for (int p = 0; p < 30; ++p) acc += ua[p] * w[p];
                            } else {
#pragma unroll
                                for (int p = 0; p < 30; ++p) acc += (ua[p] + ub[p]) * w[p];
                            }
                            emitq(a, b, acc);
                        }
                        ++k;
                    }
                if (q == 3) {
                    float w2[4];
#pragma unroll
                    for (int p = 0; p < 4; ++p) w2[p] = w2_1o[(s * 4 + p) * CC + c];
#pragma unroll 1
                    for (int j = 0; j < 9; ++j) {
                        const float* u = u2_1o + (size_t)(((sec * 9 + i) * 9 + j)) * 4;
                        float acc = 0.f;
#pragma unroll
                        for (int p = 0; p < 4; ++p) acc += u[p] * w2[p];
                        emitl(j, acc);
                    }
                }
            } else {
                float w[23];
#pragma unroll
                for (int p = 0; p < 23; ++p) w[p] = w3_0e[(s * 23 + p) * CC + c];
                int k = 0;
#pragma unroll 1
                for (int a = 0; a < 9; ++a)
#pragma unroll 1
                    for (int b = a; b < 9; ++b) {
                        if (k >= pa && k < pb) {
                            const float* ua = u3_0e + (size_t)(((i * 9 + a) * 9 + b)) * 23;
                            const float* ub = u3_0e + (size_t)(((i * 9 + b) * 9 + a)) * 23;
                            float acc = 0.f;
                            if (a == b) {
#pragma unroll
                                for (int p = 0; p < 23; ++p) acc += ua[p] * w[p];
                            } else {
#pragma unroll
                                for (int p = 0; p < 23; ++p) acc += (ua[p] + ub[p]) * w[p];
                            }
                            emitq(a, b, acc);
                        }
                        ++k;
                    }
                if (q == 3) {
                    float w2[4];
#pragma unroll
                    for (int p = 0; p < 4; ++p) w2[p] = w2_0e[(s * 4 + p) * CC + c];
#pragma unroll 1
                    for (int j = 0; j < 9; ++j) {
                        const float* u = u2_0e + (size_t)((i * 9 + j)) * 4;
                        float acc = 0.f;
#pragma unroll
                        for (int p = 0; p < 4; ++p) acc += u[p] * w2[p];
                        emitl(j, acc);
                    }
                }
            }
        } else if (idx == 9 && q == 0) {
            if (sec < 3) {
                float wv = w1_1o[s * CC + c];
#pragma unroll 1
                for (int i = 0; i < 9; ++i) emitl(i, u1_1o[sec * 9 + i] * wv);
            } else {
                float wv = w1_0e[s * CC + c];
#pragma unroll 1
                for (int i = 0; i < 9; ++i) emitl(i, u1_0e[i] * wv);
            }
        }
        // idx 10,11: zeros already staged
        __syncthreads();   // fence before typed readback (R10 TBAA lesson)
        int blk = row >> 4, r16 = row & 15;
#pragma unroll 1
        for (int j = t; j < 1536; j += 512) {
            int c2 = j / 12, chunk = j % 12;
            int h = chunk >> 2, g = chunk & 3;
            uint4 v = *(uint4*)&rowbuf[c2 * 48 + chunk * 4];
            u16* dst = af + (size_t)(c2 * SS + s) * AFRAG_U16
                          + (size_t)((blk * 3 + h) * 64 + g * 16 + r16) * 8;
            *(uint4*)dst = v;
        }
        return;
    }
    // ---- prepf: 2 sub-blocks per block ----
    {
        int b = (bid - (SC_BLK + P2_BLK)) * 2 + (t >> 8);   // 0..175
        int tl = t & 255;
        int lane = tl & 63, ck = tl >> 6;
        if (b < 160) {
            int s = b >> 4, kt = b & 15;
            int k = kt * 16 + (lane & 15);
            u16* dst = gkf + (((size_t)b * 4 + ck) * 64 + lane) * 8;
            const float* src = gk + (size_t)s * CC * 256;
#pragma unroll
            for (int e = 0; e < 8; ++e) {
                int c = ck * 32 + ((lane >> 4) & 3) * 8 + e;
                dst[e] = bf16rne(src[c * 256 + k]);
            }
        } else {
            int bb = b - 160;
            int kt = bb & 7;
            int k = kt * 16 + (lane & 15);
            const float* src = (bb >> 3) ? lin1 : lin0;
            u16* dst = linf + (((size_t)bb * 4 + ck) * 64 + lane) * 8;
#pragma unroll
            for (int e = 0; e < 8; ++e) {
                int c = ck * 32 + ((lane >> 4) & 3) * 8 + e;
                dst[e] = bf16rne(src[c * CC + k]);
            }
        }
    }
}

// ---------------- per-lane full-node x load ----------------
__device__ __forceinline__ void loadx(const float* __restrict__ nf, int n, int c,
                                      float* __restrict__ x) {
    if (n >= 0) {
        const float* r = nf + (size_t)n * 1152;
        x[0] = r[c];
        const float* r3 = r + 128 + c * 3;
        x[1] = r3[0]; x[2] = r3[1]; x[3] = r3[2];
        const float* r5 = r + 512 + c * 5;
        x[4] = r5[0]; x[5] = r5[1]; x[6] = r5[2]; x[7] = r5[3]; x[8] = r5[4];
    } else {
#pragma unroll
        for (int i = 0; i < 9; ++i) x[i] = 0.f;
    }
}

// ---------------- symmetric contraction via MFMA (per-wave, LDS-free) ----------
__global__ __launch_bounds__(128) void k_contract(
    const float* __restrict__ nf, const int* __restrict__ order,
    const int* __restrict__ blk_sp, const int* __restrict__ vend,
    const u16* __restrict__ af_g,
    float* __restrict__ f0t, float* __restrict__ f1t) {
    int bid = blockIdx.x;                 // 0..5119
    int xcd = bid & 7;
    int r = bid >> 3;
    int c = xcd * 16 + (r / 40);
    int t2 = r % 40;
    int seg = t2 >> 1, half = t2 & 1;
    int s = blk_sp[seg];
    if (s < 0) return;
    int lim = seg * NPB + vend[seg];

    int tid = threadIdx.x;
    int lane = tid & 63;
    int wq = half * 2 + (tid >> 6);
    int n16 = lane & 15, gg = lane >> 4;

    const bf16x8* ab = (const bf16x8*)(af_g + (size_t)(c * SS + s) * AFRAG_U16);
    bf16x8 a00 = ab[0 * 64 + lane], a01 = ab[1 * 64 + lane], a02 = ab[2 * 64 + lane];
    bf16x8 a10 = ab[3 * 64 + lane], a11 = ab[4 * 64 + lane], a12 = ab[5 * 64 + lane];
    bf16x8 a20 = ab[6 * 64 + lane], a21 = ab[7 * 64 + lane], a22 = ab[8 * 64 + lane];

    int posw = seg * NPB + wq * 16 + n16;

    float xc[9], xn[9];
    loadx(nf, (posw < lim) ? order[posw] : -1, c, xc);
    loadx(nf, (posw + 64 < lim) ? order[posw + 64] : -1, c, xn);
    int o2 = (posw + 128 < lim) ? order[posw + 128] : -1;
    int o3 = (posw + 192 < lim) ? order[posw + 192] : -1;

#pragma unroll 1
    for (int sub = 0; sub < 16; ++sub) {
        float xf[9];
#pragma unroll
        for (int i = 0; i < 9; ++i) xf[i] = 0.f;
        if (sub < 14) loadx(nf, o2, c, xf);
        int onew = (sub < 12 && posw + (sub + 4) * 64 < lim)
                   ? order[posw + (sub + 4) * 64] : -1;

        float xa0 = (gg == 0) ? xc[0] : (gg == 1) ? xc[1] : (gg == 2) ? xc[2] : xc[3];
        float xa1 = (gg == 0) ? xc[4] : (gg == 1) ? xc[5] : (gg == 2) ? xc[6] : xc[7];
        float xa2 = (gg == 0) ? xc[8] : (gg == 1) ? 1.0f : (gg == 2) ? xc[6] : xc[7];
        uint4 q0, q1, q2;
        q0.x = pk2(xa0 * xc[0], xa0 * xc[1]);
        q0.y = pk2(xa0 * xc[2], xa0 * xc[3]);
        q0.z = pk2(xa0 * xc[4], xa0 * xc[5]);
        q0.w = pk2(xa0 * xc[6], xa0 * xc[7]);
        q1.x = pk2(xa1 * xc[0], xa1 * xc[1]);
        q1.y = pk2(xa1 * xc[2], xa1 * xc[3]);
        q1.z = pk2(xa1 * xc[4], xa1 * xc[5]);
        q1.w = pk2(xa1 * xc[6], xa1 * xc[7]);
        q2.x = pk2(xa2 * xc[8], xa2);
        q2.y = pk2(xa2 * xc[0], xa2 * xc[1]);
        q2.z = pk2(xa2 * xc[2], xa2 * xc[3]);
        q2.w = pk2(xa2 * xc[4], xa2 * xc[5]);
        bf16x8 y0 = __builtin_bit_cast(bf16x8, q0);
        bf16x8 y1 = __builtin_bit_cast(bf16x8, q1);
        bf16x8 y2 = __builtin_bit_cast(bf16x8, q2);

        f32x4 acc0 = {0.f, 0.f, 0.f, 0.f}, acc1 = acc0, acc2 = acc0;
        acc0 = __builtin_amdgcn_mfma_f32_16x16x32_bf16(a00, y0, acc0, 0, 0, 0);
        acc0 = __builtin_amdgcn_mfma_f32_16x16x32_bf16(a01, y1, acc0, 0, 0, 0);
        acc0 = __builtin_amdgcn_mfma_f32_16x16x32_bf16(a02, y2, acc0, 0, 0, 0);
        acc1 = __builtin_amdgcn_mfma_f32_16x16x32_bf16(a10, y0, acc1, 0, 0, 0);
        acc1 = __builtin_amdgcn_mfma_f32_16x16x32_bf16(a11, y1, acc1, 0, 0, 0);
        acc1 = __builtin_amdgcn_mfma_f32_16x16x32_bf16(a12, y2, acc1, 0, 0, 0);
        acc2 = __builtin_amdgcn_mfma_f32_16x16x32_bf16(a20, y0, acc2, 0, 0, 0);
        acc2 = __builtin_amdgcn_mfma_f32_16x16x32_bf16(a21, y1, acc2, 0, 0, 0);
        acc2 = __builtin_amdgcn_mfma_f32_16x16x32_bf16(a22, y2, acc2, 0, 0, 0);

        f32x4 eA = (gg == 0) ? acc0 : (gg == 1) ? acc2 : (gg == 2) ? acc1 : acc0;
        f32x4 eB = (gg == 0) ? acc1 : (gg == 1) ? acc0 : (gg == 2) ? acc2 : acc1;
        f32x4 eC = (gg == 0) ? acc2 : (gg == 1) ? acc1 : (gg == 2) ? acc0 : acc2;
        float dA = eA[0] * xc[0] + eA[1] * xc[1] + eA[2] * xc[2] + eA[3] * xc[3];
        float dB = eB[0] * xc[4] + eB[1] * xc[5] + eB[2] * xc[6] + eB[3] * xc[7];
        float dC = eC[0] * xc[8] + eC[1];
        float p0 = (gg == 0) ? dA : (gg == 1) ? dB : (gg == 2) ? dC : 0.f;
        float p1 = (gg == 0) ? dB : (gg == 1) ? dC : (gg == 2) ? 0.f : dA;
        float p2 = (gg == 0) ? dC : (gg == 1) ? 0.f : (gg == 2) ? dA : dB;
        float p3 = (gg == 0) ? 0.f : (gg == 1) ? dA : (gg == 2) ? dB : dC;
        p0 += __shfl_xor(p0, 16); p1 += __shfl_xor(p1, 16);
        p2 += __shfl_xor(p2, 16); p3 += __shfl_xor(p3, 16);
        p0 += __shfl_xor(p0, 32); p1 += __shfl_xor(p1, 32);
        p2 += __shfl_xor(p2, 32); p3 += __shfl_xor(p3, 32);
        float val = (gg == 0) ? p0 : (gg == 1) ? p1 : (gg == 2) ? p2 : p3;

        int pos = posw + sub * 64;
        if (gg == 3) f0t[(size_t)c * NPAD + pos] = val;
        else         f1t[(size_t)(c * 3 + gg) * NPAD + pos] = val;

#pragma unroll
        for (int i = 0; i < 9; ++i) { xc[i] = xn[i]; xn[i] = xf[i]; }
        o2 = o3; o3 = onew;
    }
}

// ---------------- fused gate + equivariant linear (MFMA), 2-way split ----------
#define GSTR 264
__global__ __launch_bounds__(256) void k_post(
    const float* __restrict__ f0t, const float* __restrict__ f1t,
    const u16* __restrict__ gkf, const u16* __restrict__ linf,
    const float* __restrict__ gb, const int* __restrict__ order,
    const int* __restrict__ blk_sp, const int* __restrict__ vend,
    float* __restrict__ out) {
    int tile = blockIdx.x;
    int half = blockIdx.y;
    int s = blk_sp[tile >> 4];
    if (s < 0) return;
    int p0 = tile * 64;
    int vv = vend[tile >> 4];
    int boff = (tile & 15) * 64;

    __shared__ __align__(16) u16 frag[4][4][64][8];
    __shared__ __align__(16) u16 gate_l[64 * GSTR];
    __shared__ int ord[64];

    int t = threadIdx.x, lane = t & 63, w = t >> 6;
    int l15 = lane & 15, lg = lane >> 4;
    if (t < 64) ord[t] = (boff + t < vv) ? order[p0 + t] : -1;

#pragma unroll 1
    for (int it = 0; it < 32; ++it) {
        int posn = t & 63;
        int c = (t >> 6) + 4 * it;
        float v = f0t[(size_t)c * NPAD + p0 + posn];
        frag[posn >> 4][c >> 5][((c >> 3) & 3) * 16 + (posn & 15)][c & 7] = bf16rne(v);
    }
    __syncthreads();

#pragma unroll 1
    for (int kt = 0; kt < 16; ++kt) {
        float bias = gb[s * 256 + kt * 16 + l15];
        f32x4 acc = {bias, bias, bias, bias};
#pragma unroll
        for (int ck = 0; ck < 4; ++ck) {
            bf16x8 a = *(const bf16x8*)&frag[w][ck][lane][0];
            bf16x8 b = *(const bf16x8*)&gkf[(((size_t)(s * 16 + kt)) * 4 + ck) * 512 + lane * 8];
            acc = __builtin_amdgcn_mfma_f32_16x16x32_bf16(a, b, acc, 0, 0, 0);
        }
#pragma unroll
        for (int r = 0; r < 4; ++r) {
            int posn = w * 16 + lg * 4 + r;
            gate_l[posn * GSTR + kt * 16 + l15] = bf16rne(acc[r]);
        }
    }
    __syncthreads();

    const float INV = 0.08838834764831845f;   // 1/sqrt(128)

#pragma unroll 1
    for (int p = 2 * half; p < 2 * half + 2; ++p) {
#pragma unroll 1
        for (int it = 0; it < 4; ++it) {
            int rr = it * 256 + t;
            int pt = rr >> 8, ck = (rr >> 6) & 3, l2 = rr & 63;
            int posn = pt * 16 + (l2 & 15);
            int cb = ck * 32 + (l2 >> 4) * 8;
            u16 res[8];
            if (p == 0) {
                bf16x8 a1 = *(const bf16x8*)&frag[pt][ck][l2][0];
                const u16* gp = &gate_l[posn * GSTR + cb];
#pragma unroll
                for (int e = 0; e < 8; ++e)
                    res[e] = bf16rne(bf2f((u16)a1[e]) * bf2f(gp[e]));
            } else {
                int z = p - 1;
                const u16* gp = &gate_l[posn * GSTR + 128 + cb];
#pragma unroll
                for (int e = 0; e < 8; ++e) {
                    float fv = f1t[((size_t)(cb + e) * 3 + z) * NPAD + p0 + posn];
                    res[e] = bf16rne(fv * bf2f(gp[e]));
                }
            }
            uint4 uv;
            uv.x = (unsigned)res[0] | ((unsigned)res[1] << 16);
            uv.y = (unsigned)res[2] | ((unsigned)res[3] << 16);
            uv.z = (unsigned)res[4] | ((unsigned)res[5] << 16);
            uv.w = (unsigned)res[6] | ((unsigned)res[7] << 16);
            *(uint4*)&frag[pt][ck][l2][0] = uv;
        }
        __syncthreads();

        int lbase = (p == 0) ? 0 : 8;
#pragma unroll 1
        for (int kt = 0; kt < 8; ++kt) {
            f32x4 acc = {0.f, 0.f, 0.f, 0.f};
#pragma unroll
            for (int ck = 0; ck < 4; ++ck) {
                bf16x8 a = *(const bf16x8*)&frag[w][ck][lane][0];
                bf16x8 b = *(const bf16x8*)&linf[(((size_t)(lbase + kt)) * 4 + ck) * 512 + lane * 8];
                acc = __builtin_amdgcn_mfma_f32_16x16x32_bf16(a, b, acc, 0, 0, 0);
            }
            int k = kt * 16 + l15;
            int kk = (p == 0) ? k : (128 + k * 3 + (p - 1));
#pragma unroll
            for (int r = 0; r < 4; ++r) {
                int posn = w * 16 + lg * 4 + r;
                int n = ord[posn];
                if (n >= 0) out[(size_t)n * 512 + kk] = acc[r] * INV;
            }
        }
        __syncthreads();
    }
}

// ---------------------------------------------------------------------------
extern "C" void kernel_launch(void* const* d_in, const int* in_sizes, int n_in,
                              void* d_out, int out_size, void* d_ws, size_t ws_size,
                              hipStream_t stream) {
    const float* nf    = (const float*)d_in[0];
    const int*   sp    = (const int*)  d_in[1];
    const float* u1_0e = (const float*)d_in[2];
    const float* u2_0e = (const float*)d_in[3];
    const float* u3_0e = (const float*)d_in[4];
    const float* u1_1o = (const float*)d_in[5];
    const float* u2_1o = (const float*)d_in[6];
    const float* u3_1o = (const float*)d_in[7];
    const float* w1_0e = (const float*)d_in[8];
    const float* w2_0e = (const float*)d_in[9];
    const float* w3_0e = (const float*)d_in[10];
    const float* w1_1o = (const float*)d_in[11];
    const float* w2_1o = (const float*)d_in[12];
    const float* w3_1o = (const float*)d_in[13];
    const float* gk    = (const float*)d_in[14];
    const float* gb    = (const float*)d_in[15];
    const float* lin0  = (const float*)d_in[16];
    const float* lin1  = (const float*)d_in[17];

    float* ws   = (float*)d_ws;
    u16*  af    = (u16*)(ws + OFF_AF);
    float* f0t  = ws + OFF_F0;
    float* f1t  = ws + OFF_F1;
    u16*  gkf   = (u16*)(ws + OFF_GKF);
    u16*  linf  = (u16*)(ws + OFF_LINF);
    int* order  = (int*)(ws + OFF_ORD);
    int* meta   = (int*)(ws + OFF_META);
    int* cursor = meta + 16;
    int* blk_sp = meta + 32;
    int* vend   = meta + 64;

    k_plan<<<1, 256, 0, stream>>>(sp, cursor, blk_sp, vend);
    k_setup2<<<SC_BLK + P2_BLK + 88, 512, 0, stream>>>(
        sp, cursor, order,
        u1_0e, u2_0e, u3_0e, u1_1o, u2_1o, u3_1o,
        w1_0e, w2_0e, w3_0e, w1_1o, w2_1o, w3_1o, af,
        gk, lin0, lin1, gkf, linf);
    k_contract<<<5120, 128, 0, stream>>>(nf, order, blk_sp, vend, af, f0t, f1t);
    dim3 gpost(NPAD / 64, 2);
    k_post<<<gpost, 256, 0, stream>>>(f0t, f1t, gkf, linf, gb, order, blk_sp, vend,
                                      (float*)d_out);
}